// Round 3
// baseline (136.715 us; speedup 1.0000x reference)
//
#include <hip/hip_runtime.h>

namespace {
constexpr int kB = 8192;   // batch
constexpr int kD = 768;    // emb dim
constexpr int kM = 96;     // subvectors
constexpr int kK = 256;    // codes per subvector
constexpr int kDS = 8;     // dsub
constexpr int kThreads = 256;
constexpr int kBPT = 4;                    // b's per thread
constexpr int kBT = kThreads * kBPT;       // 1024 b per block
}

// np.sum pairwise tree for n=8: ((q0+q1)+(q2+q3)) + ((q4+q5)+(q6+q7))
__device__ __forceinline__ float tree8_sq(float4 a, float4 b) {
    float q0 = __fmul_rn(a.x, a.x), q1 = __fmul_rn(a.y, a.y);
    float q2 = __fmul_rn(a.z, a.z), q3 = __fmul_rn(a.w, a.w);
    float q4 = __fmul_rn(b.x, b.x), q5 = __fmul_rn(b.y, b.y);
    float q6 = __fmul_rn(b.z, b.z), q7 = __fmul_rn(b.w, b.w);
    return __fadd_rn(__fadd_rn(__fadd_rn(q0, q1), __fadd_rn(q2, q3)),
                     __fadd_rn(__fadd_rn(q4, q5), __fadd_rn(q6, q7)));
}

__global__ __launch_bounds__(kThreads)
void pq_argmax_kernel(const float* __restrict__ vecs,
                      const float* __restrict__ cb,
                      float* __restrict__ out) {
    __shared__ float s_cb[kK * kDS];   // 8 KB: codebook[m]
    __shared__ float s_c2[kK];         // 1 KB: ||c||^2

    const int tid = threadIdx.x;
    const int m  = blockIdx.x % kM;
    const int bt = blockIdx.x / kM;

    // Stage codebook slice for this m. Thread t loads code row k=t (32 B,
    // consecutive threads -> consecutive 32B chunks: fully coalesced).
    {
        const float4* src = reinterpret_cast<const float4*>(cb) + (size_t)m * (kK * kDS / 4);
        float4 a = src[2 * tid + 0];
        float4 b = src[2 * tid + 1];
        reinterpret_cast<float4*>(s_cb)[2 * tid + 0] = a;
        reinterpret_cast<float4*>(s_cb)[2 * tid + 1] = b;
        s_c2[tid] = tree8_sq(a, b);    // np tree-of-8 order
    }
    __syncthreads();

    const int b0 = bt * kBT + tid;

    // Load 4 b-rows' subvectors for this m (32 B each) + their v2.
    float v[kBPT][kDS];
    float v2[kBPT];
#pragma unroll
    for (int j = 0; j < kBPT; ++j) {
        const float* vr = vecs + (size_t)(b0 + j * kThreads) * kD + m * kDS;
        float4 a = reinterpret_cast<const float4*>(vr)[0];
        float4 b = reinterpret_cast<const float4*>(vr)[1];
        v[j][0] = a.x; v[j][1] = a.y; v[j][2] = a.z; v[j][3] = a.w;
        v[j][4] = b.x; v[j][5] = b.y; v[j][6] = b.z; v[j][7] = b.w;
        v2[j] = tree8_sq(a, b);        // np tree-of-8 order
    }

    float best[kBPT];
    int   bestk[kBPT];
#pragma unroll
    for (int j = 0; j < kBPT; ++j) { best[j] = -3.402823466e38f; bestk[j] = 0; }

    // Argmax over the 256 codes. LDS reads are wave-uniform -> broadcast.
#pragma unroll 4
    for (int k = 0; k < kK; ++k) {
        float4 ca  = reinterpret_cast<const float4*>(s_cb)[2 * k + 0];
        float4 cbv = reinterpret_cast<const float4*>(s_cb)[2 * k + 1];
        float  c2k = s_c2[k];
#pragma unroll
        for (int j = 0; j < kBPT; ++j) {
            // einsum semantics: sequential mul-then-add, NO fma contraction
            float acc = __fmul_rn(v[j][0], ca.x);
            acc = __fadd_rn(acc, __fmul_rn(v[j][1], ca.y));
            acc = __fadd_rn(acc, __fmul_rn(v[j][2], ca.z));
            acc = __fadd_rn(acc, __fmul_rn(v[j][3], ca.w));
            acc = __fadd_rn(acc, __fmul_rn(v[j][4], cbv.x));
            acc = __fadd_rn(acc, __fmul_rn(v[j][5], cbv.y));
            acc = __fadd_rn(acc, __fmul_rn(v[j][6], cbv.z));
            acc = __fadd_rn(acc, __fmul_rn(v[j][7], cbv.w));
            // reference order: (2*vc - v2) - c2, fp32 rounding at each step
            float p = __fsub_rn(__fsub_rn(__fmul_rn(2.0f, acc), v2[j]), c2k);
            // strict '>' ascending k == np.argmax first-index-wins tie-break
            bool gt = p > best[j];
            best[j]  = gt ? p : best[j];
            bestk[j] = gt ? k : bestk[j];
        }
    }

    // Output = exact copy of the winning code row (bitwise == reference).
#pragma unroll
    for (int j = 0; j < kBPT; ++j) {
        const float4* q = reinterpret_cast<const float4*>(s_cb) + 2 * bestk[j];
        float4* o = reinterpret_cast<float4*>(out + (size_t)(b0 + j * kThreads) * kD + m * kDS);
        o[0] = q[0];
        o[1] = q[1];
    }
}

extern "C" void kernel_launch(void* const* d_in, const int* in_sizes, int n_in,
                              void* d_out, int out_size, void* d_ws, size_t ws_size,
                              hipStream_t stream) {
    const float* vecs = (const float*)d_in[0];   // (8192, 768) fp32
    const float* cb   = (const float*)d_in[1];   // (96, 256, 8) fp32
    float* out = (float*)d_out;                  // (8192, 768) fp32

    dim3 grid(kM * (kB / kBT));                  // 96 * 8 = 768 blocks
    pq_argmax_kernel<<<grid, kThreads, 0, stream>>>(vecs, cb, out);
}